// Round 2
// baseline (353.538 us; speedup 1.0000x reference)
//
#include <hip/hip_runtime.h>
#include <math.h>

// Quantize/dequantize with 64-level sorted codebook.
// symbols = argmin_j |codebook[j] - (x - means)|  (tie -> lower index)
// y_hat   = codebook[symbols] + means
//
// Strategy: symbol = #{ mid[j] < r } (strict <, mid = 0.5*(cb[j]+cb[j+1]),
// matching reference tie rule). Instead of a 6-step binary search per
// element, use a 1024-cell uniform LUT over [cb[0], cb[63]]:
//   LUT[c] = #{ mids m : cell(m) < c }   (cell() identical in build & query)
// which is a provably <=-correct starting position for every r in cell c;
// a scan-up "while (mid[pos] < r) ++pos" (usually 1 compare) finishes.
// Output is bit-identical to the binary-search kernel.

#define NCELL 1024

// native vector type for nontemporal stores (HIP float4 is a class type,
// rejected by __builtin_nontemporal_store)
typedef float f32x4 __attribute__((ext_vector_type(4)));

__device__ __forceinline__ int cellof(float v, float lo, float scale) {
    // Monotone nondecreasing in v; MUST be the same ops at build and query.
    float t = (v - lo) * scale;
    t = fminf(fmaxf(t, 0.0f), (float)(NCELL - 1));
    return (int)t;                        // trunc
}

__global__ __launch_bounds__(256) void quant_dequant_kernel(
    const float4* __restrict__ x4,
    const float4* __restrict__ m4,
    const float*  __restrict__ codebook,
    f32x4* __restrict__ sym_out,   // symbols as float values
    f32x4* __restrict__ yhat_out,
    int n4)
{
    __shared__ float s_cb[64];
    __shared__ float s_mid[64];              // 63 midpoints + INF sentinel
    __shared__ unsigned short s_fm[64];      // cell index of each midpoint, sorted; 0xFFFF pad
    __shared__ unsigned short s_lut[NCELL];  // lower_bound start positions

    const int tid = threadIdx.x;
    if (tid < 64) s_cb[tid] = codebook[tid];
    __syncthreads();
    if (tid < 64)
        s_mid[tid] = (tid < 63) ? 0.5f * (s_cb[tid] + s_cb[tid + 1])
                                : INFINITY;
    const float lo    = s_cb[0];
    const float hi    = s_cb[63];
    const float range = hi - lo;
    const float scale = (range > 0.0f) ? ((float)NCELL / range) : 0.0f;
    __syncthreads();
    if (tid < 64)
        s_fm[tid] = (tid < 63) ? (unsigned short)cellof(s_mid[tid], lo, scale)
                               : (unsigned short)0xFFFF;  // sentinel >= NCELL
    __syncthreads();

    // LUT[c] = lower_bound(s_fm[0..62], c) = #{ i : fm[i] < c }, branchless
    // 6-step search over the 64-entry padded array (pad never counted: 0xFFFF >= NCELL > c).
#pragma unroll
    for (int e = 0; e < NCELL / 256; ++e) {
        const int c = tid + e * 256;
        int pos = 0;
#pragma unroll
        for (int s = 32; s > 0; s >>= 1)
            pos += (s_fm[pos + s - 1] < c) ? s : 0;
        s_lut[c] = (unsigned short)pos;
    }
    __syncthreads();

    const int stride = gridDim.x * blockDim.x;
    int i = blockIdx.x * blockDim.x + tid;

    // main loop: 4 float4 (16 elements) per outer iteration -> 8 dwordx4
    // loads in flight per wave for HBM latency hiding.
    for (; i + 3 * stride < n4; i += 4 * stride) {
        float4 xv[4], mv[4];
#pragma unroll
        for (int u = 0; u < 4; ++u) {
            xv[u] = x4[i + u * stride];
            mv[u] = m4[i + u * stride];
        }
#pragma unroll
        for (int u = 0; u < 4; ++u) {
            float rr[4] = { xv[u].x - mv[u].x, xv[u].y - mv[u].y,
                            xv[u].z - mv[u].z, xv[u].w - mv[u].w };
            float mm[4] = { mv[u].x, mv[u].y, mv[u].z, mv[u].w };
            f32x4 sy, yh;
#pragma unroll
            for (int k = 0; k < 4; ++k) {
                const float r = rr[k];
                const int idx = cellof(r, lo, scale);
                int pos = (int)s_lut[idx];
                while (s_mid[pos] < r) ++pos;   // usually exits on first compare
                sy[k] = (float)pos;
                yh[k] = s_cb[pos] + mm[k];
            }
            __builtin_nontemporal_store(sy, &sym_out[i + u * stride]);
            __builtin_nontemporal_store(yh, &yhat_out[i + u * stride]);
        }
    }
    // remainder
    for (; i < n4; i += stride) {
        const float4 xv = x4[i];
        const float4 mv = m4[i];
        float rr[4] = { xv.x - mv.x, xv.y - mv.y, xv.z - mv.z, xv.w - mv.w };
        float mm[4] = { mv.x, mv.y, mv.z, mv.w };
        f32x4 sy, yh;
#pragma unroll
        for (int k = 0; k < 4; ++k) {
            const float r = rr[k];
            const int idx = cellof(r, lo, scale);
            int pos = (int)s_lut[idx];
            while (s_mid[pos] < r) ++pos;
            sy[k] = (float)pos;
            yh[k] = s_cb[pos] + mm[k];
        }
        __builtin_nontemporal_store(sy, &sym_out[i]);
        __builtin_nontemporal_store(yh, &yhat_out[i]);
    }
}

extern "C" void kernel_launch(void* const* d_in, const int* in_sizes, int n_in,
                              void* d_out, int out_size, void* d_ws, size_t ws_size,
                              hipStream_t stream)
{
    const float* x     = (const float*)d_in[0];
    const float* means = (const float*)d_in[1];
    const float* cb    = (const float*)d_in[2];

    const int n  = in_sizes[0];      // 25,165,824
    const int n4 = n / 4;            // 6,291,456 (divisible)

    float* out = (float*)d_out;      // [0..n): symbols (as float), [n..2n): y_hat

    const int block = 256;
    const int grid  = 2048;          // grid-stride: 8 blocks/CU, 12 float4/thread

    quant_dequant_kernel<<<grid, block, 0, stream>>>(
        (const float4*)x, (const float4*)means, cb,
        (f32x4*)out, (f32x4*)(out + n), n4);
}

// Round 3
// 346.288 us; speedup vs baseline: 1.0209x; 1.0209x over previous
//
#include <hip/hip_runtime.h>
#include <math.h>

// Quantize/dequantize with 64-level sorted codebook.
// symbols = argmin_j |codebook[j] - (x - means)|  (tie -> lower index)
// y_hat   = codebook[symbols] + means
//
// symbol = #{ mid[j] < r } (strict <, mid = 0.5*(cb[j]+cb[j+1]), matches
// reference tie rule). A 1024-cell uniform LUT over [cb[0], cb[63]] gives
// lower_bound start positions; the fixup is a BRANCHLESS sum of W
// independent compares, where W = max #midpoints in any cell (block-uniform,
// computed by a 1-block pre-kernel into d_ws). Correctness for any codebook:
//   - mids with cell < c satisfy mid < r (cellof monotone)  -> pre-counted
//   - mids with cell > c satisfy mid > r                    -> contribute 0
//   - extra reads past the window hit INF padding           -> contribute 0
// Output is bit-identical to the original binary-search kernel.

#define NCELL 1024

__device__ __forceinline__ int cellof(float v, float lo, float scale) {
    // Monotone nondecreasing; MUST be identical ops at build and query.
    float t = (v - lo) * scale;
    t = fminf(fmaxf(t, 0.0f), (float)(NCELL - 1));
    return (int)t;
}

// ---------------- pre-kernel: build mid[64], lut[1024], W into workspace ----
__global__ __launch_bounds__(256) void build_lut_kernel(
    const float* __restrict__ codebook,
    float* __restrict__ ws_mid,            // [64] midpoints (+INF sentinel)
    unsigned short* __restrict__ ws_lut,   // [NCELL]
    unsigned int* __restrict__ ws_w)       // [1] max mids per cell
{
    __shared__ float s_cb[64];
    __shared__ unsigned short s_fm[64];
    __shared__ unsigned int s_lut32[NCELL / 2];
    __shared__ unsigned int s_red[4];
    unsigned short* s_lut = (unsigned short*)s_lut32;

    const int tid = threadIdx.x;
    if (tid < 64) s_cb[tid] = codebook[tid];
    __syncthreads();
    const float lo    = s_cb[0];
    const float range = s_cb[63] - lo;
    const float scale = (range > 0.0f) ? ((float)NCELL / range) : 0.0f;
    if (tid < 64) {
        float mid = (tid < 63) ? 0.5f * (s_cb[tid] + s_cb[tid + 1]) : INFINITY;
        ws_mid[tid] = mid;
        s_fm[tid] = (tid < 63) ? (unsigned short)cellof(mid, lo, scale)
                               : (unsigned short)0xFFFF;  // sentinel >= NCELL
    }
    __syncthreads();

    unsigned short myl[NCELL / 256];
#pragma unroll
    for (int e = 0; e < NCELL / 256; ++e) {
        const int c = tid + e * 256;
        int pos = 0;  // lower_bound(s_fm[0..62], c); pad 0xFFFF never counted
#pragma unroll
        for (int s = 32; s > 0; s >>= 1)
            pos += (s_fm[pos + s - 1] < c) ? s : 0;
        myl[e] = (unsigned short)pos;
        s_lut[c] = (unsigned short)pos;
    }
    __syncthreads();

    unsigned int mymax = 0;
#pragma unroll
    for (int e = 0; e < NCELL / 256; ++e) {
        const int c = tid + e * 256;
        unsigned int nxt = (c == NCELL - 1) ? 63u : (unsigned int)s_lut[c + 1];
        mymax = max(mymax, nxt - (unsigned int)myl[e]);
        ws_lut[c] = myl[e];
    }
#pragma unroll
    for (int off = 32; off > 0; off >>= 1)
        mymax = max(mymax, (unsigned int)__shfl_down((int)mymax, off));
    if ((tid & 63) == 0) s_red[tid >> 6] = mymax;
    __syncthreads();
    if (tid == 0) {
        unsigned int w = max(max(s_red[0], s_red[1]), max(s_red[2], s_red[3]));
        *ws_w = (w < 1u) ? 1u : w;
    }
}

// ---------------- main kernel ----------------------------------------------
__device__ __forceinline__ void process4(
    const float4 xv, const float4 mv,
    const float lo, const float scale, const int W,
    const float* s_cb, const float* s_mid, const unsigned short* s_lut,
    float4& sy, float4& yh)
{
    float rr[4] = { xv.x - mv.x, xv.y - mv.y, xv.z - mv.z, xv.w - mv.w };
    float mm[4] = { mv.x, mv.y, mv.z, mv.w };
    float sv[4], yv[4];
    if (W <= 2) {  // block-uniform branch; typical path, fully unrolled
#pragma unroll
        for (int k = 0; k < 4; ++k) {
            const float r = rr[k];
            const int start = (int)s_lut[cellof(r, lo, scale)];
            const int pos = start + ((s_mid[start] < r) ? 1 : 0)
                                  + ((s_mid[start + 1] < r) ? 1 : 0);
            sv[k] = (float)pos;
            yv[k] = s_cb[pos] + mm[k];
        }
    } else {       // rare degenerate codebooks; still branchless per element
#pragma unroll
        for (int k = 0; k < 4; ++k) {
            const float r = rr[k];
            const int start = (int)s_lut[cellof(r, lo, scale)];
            int pos = start;
            for (int j = 0; j < W; ++j)
                pos += (s_mid[start + j] < r) ? 1 : 0;
            sv[k] = (float)pos;
            yv[k] = s_cb[pos] + mm[k];
        }
    }
    sy = make_float4(sv[0], sv[1], sv[2], sv[3]);
    yh = make_float4(yv[0], yv[1], yv[2], yv[3]);
}

__global__ __launch_bounds__(256) void quant_dequant_kernel(
    const float4* __restrict__ x4,
    const float4* __restrict__ m4,
    const float*  __restrict__ codebook,
    const float*  __restrict__ ws_mid,
    const unsigned int* __restrict__ ws_lut32,  // lut as u32[NCELL/2]
    const unsigned int* __restrict__ ws_w,
    float4* __restrict__ sym_out,
    float4* __restrict__ yhat_out,
    int n4)
{
    __shared__ float s_cb[64];
    __shared__ float s_mid[128];   // 63 mids + INF padding through index 127
    __shared__ unsigned int s_lut32[NCELL / 2];
    __shared__ unsigned int s_wv;
    const unsigned short* s_lut = (const unsigned short*)s_lut32;

    const int tid = threadIdx.x;
    if (tid < 64)  s_cb[tid]  = codebook[tid];
    if (tid < 128) s_mid[tid] = (tid < 64) ? ws_mid[tid] : INFINITY;
    s_lut32[tid]       = ws_lut32[tid];
    s_lut32[tid + 256] = ws_lut32[tid + 256];
    if (tid == 0) s_wv = *ws_w;
    __syncthreads();

    const float lo    = s_cb[0];
    const float range = s_cb[63] - lo;
    const float scale = (range > 0.0f) ? ((float)NCELL / range) : 0.0f;
    const int   W     = (int)s_wv;

    const int stride = gridDim.x * blockDim.x;
    const int step   = 2 * stride;
    const int n4_main = n4 - (n4 % step);

    int base = blockIdx.x * blockDim.x + tid;
    if (base < n4_main) {
        // software pipeline: next iteration's loads issued BEFORE processing
        // the current registers, so 4 dwordx4 stay in flight during compute.
        float4 ax0 = x4[base], ax1 = x4[base + stride];
        float4 am0 = m4[base], am1 = m4[base + stride];
        int nb = base + step;
        while (true) {
            float4 bx0, bx1, bm0, bm1;
            const bool more = (nb < n4_main);  // uniform across the grid
            if (more) {
                bx0 = x4[nb]; bx1 = x4[nb + stride];
                bm0 = m4[nb]; bm1 = m4[nb + stride];
            }
            float4 sy0, yh0, sy1, yh1;
            process4(ax0, am0, lo, scale, W, s_cb, s_mid, s_lut, sy0, yh0);
            process4(ax1, am1, lo, scale, W, s_cb, s_mid, s_lut, sy1, yh1);
            sym_out[base]           = sy0;
            yhat_out[base]          = yh0;
            sym_out[base + stride]  = sy1;
            yhat_out[base + stride] = yh1;
            if (!more) break;
            ax0 = bx0; ax1 = bx1; am0 = bm0; am1 = bm1;
            base = nb; nb += step;
        }
    }
    // tail (empty for the benchmark shape)
    for (int i = n4_main + blockIdx.x * blockDim.x + tid; i < n4; i += stride) {
        float4 sy, yh;
        process4(x4[i], m4[i], lo, scale, W, s_cb, s_mid, s_lut, sy, yh);
        sym_out[i]  = sy;
        yhat_out[i] = yh;
    }
}

extern "C" void kernel_launch(void* const* d_in, const int* in_sizes, int n_in,
                              void* d_out, int out_size, void* d_ws, size_t ws_size,
                              hipStream_t stream)
{
    const float* x     = (const float*)d_in[0];
    const float* means = (const float*)d_in[1];
    const float* cb    = (const float*)d_in[2];

    const int n  = in_sizes[0];      // 25,165,824
    const int n4 = n / 4;            // 6,291,456 (divisible)

    float* out = (float*)d_out;      // [0..n): symbols (as float), [n..2n): y_hat

    // workspace layout: mid f32[64] | lut u16[1024] | W u32
    float*          ws_mid = (float*)d_ws;
    unsigned short* ws_lut = (unsigned short*)((char*)d_ws + 256);
    unsigned int*   ws_w   = (unsigned int*)((char*)d_ws + 256 + 2048);

    build_lut_kernel<<<1, 256, 0, stream>>>(cb, ws_mid, ws_lut, ws_w);

    const int block = 256;
    const int grid  = 2048;          // 12 float4/thread, U=2 pipelined
    quant_dequant_kernel<<<grid, block, 0, stream>>>(
        (const float4*)x, (const float4*)means, cb,
        ws_mid, (const unsigned int*)ws_lut, ws_w,
        (float4*)out, (float4*)(out + n), n4);
}

// Round 4
// 335.832 us; speedup vs baseline: 1.0527x; 1.0311x over previous
//
#include <hip/hip_runtime.h>
#include <math.h>

// Quantize/dequantize with 64-level sorted codebook.
// symbols = argmin_j |codebook[j] - (x - means)|  (tie -> lower index)
// y_hat   = codebook[symbols] + means
//
// symbol = #{ mid[j] < r } (strict <, mid = 0.5*(cb[j]+cb[j+1]); matches
// reference tie rule). A 1024-cell uniform LUT over [cb[0], cb[63]]:
// per cell c: epos = {pos = #mids in cells < c, n = #mids in cell c},
//             emid = first mid in cell c (INF if none).
// Query: pos += (emid < r); rare n>1 cells scan s_mid[pos0+1..pos0+n-1].
// cellof() is the identical monotone function at build and query, so
// mids in lower cells are < r and mids in higher cells are > r; output is
// bit-identical to the original binary-search kernel.
//
// Structure lesson from rounds 0-3: flat grid with quick-retiring blocks
// drives HBM (~4.5 TB/s); grid-stride loops at 2048 blocks do not (2.3 TB/s).

#define NCELL 1024

__device__ __forceinline__ int cellof(float v, float lo, float scale) {
    float t = (v - lo) * scale;                 // sub+mul, no fma contraction
    t = fminf(fmaxf(t, 0.0f), (float)(NCELL - 1));
    return (int)t;
}

// ---------------- pre-kernel: build emid[1024], epos[1024], mid[64] --------
__global__ __launch_bounds__(256) void build_lut_kernel(
    const float* __restrict__ codebook,
    float* __restrict__ ws_mid,        // [64] midpoints (+INF sentinel at 63)
    float* __restrict__ ws_emid,       // [NCELL]
    unsigned int* __restrict__ ws_epos)// [NCELL]  pos | (n<<16)
{
    __shared__ float s_cb[64];
    __shared__ float s_mid[64];
    __shared__ unsigned short s_fm[64];

    const int tid = threadIdx.x;
    if (tid < 64) s_cb[tid] = codebook[tid];
    __syncthreads();
    const float lo    = s_cb[0];
    const float range = s_cb[63] - lo;
    const float scale = (range > 0.0f) ? ((float)NCELL / range) : 0.0f;
    if (tid < 64) {
        float mid = (tid < 63) ? 0.5f * (s_cb[tid] + s_cb[tid + 1]) : INFINITY;
        s_mid[tid]  = mid;
        ws_mid[tid] = mid;
        s_fm[tid] = (tid < 63) ? (unsigned short)cellof(mid, lo, scale)
                               : (unsigned short)0xFFFF;  // sentinel >= NCELL
    }
    __syncthreads();

#pragma unroll
    for (int e = 0; e < NCELL / 256; ++e) {
        const int c = tid + e * 256;
        // lower_bound(s_fm[0..62], c): #mids in cells < c (pad never counted)
        int pos = 0;
#pragma unroll
        for (int s = 32; s > 0; s >>= 1)
            pos += (s_fm[pos + s - 1] < c) ? s : 0;
        // lower_bound(s_fm, c+1): #mids in cells <= c
        int pos1 = 0;
#pragma unroll
        for (int s = 32; s > 0; s >>= 1)
            pos1 += (s_fm[pos1 + s - 1] < c + 1) ? s : 0;
        const int n = pos1 - pos;                 // #mids in cell c
        ws_emid[c] = (n > 0) ? s_mid[pos] : INFINITY;
        ws_epos[c] = (unsigned int)pos | ((unsigned int)n << 16);
    }
}

// ---------------- main kernel: flat grid, 2 float4/thread, quick retire ----
__global__ __launch_bounds__(256) void quant_dequant_kernel(
    const float4* __restrict__ x4,
    const float4* __restrict__ m4,
    const float*  __restrict__ codebook,
    const float*  __restrict__ ws_mid,
    const float4* __restrict__ ws_emid4,        // emid as float4[NCELL/4]
    const uint4*  __restrict__ ws_epos4,        // epos as uint4[NCELL/4]
    float4* __restrict__ sym_out,
    float4* __restrict__ yhat_out,
    int n4)
{
    __shared__ float        s_emid[NCELL];
    __shared__ unsigned int s_epos[NCELL];
    __shared__ float        s_cb[64];
    __shared__ float        s_mid[64];

    const int tid = threadIdx.x;

    // setup loads first (L2-hot, ~8.75 KB per block)
    const float4 ev  = ws_emid4[tid];
    const uint4  pv  = ws_epos4[tid];
    const float  cbv  = (tid < 64) ? codebook[tid] : 0.0f;
    const float  midv = (tid < 64) ? ws_mid[tid]   : 0.0f;

    // payload loads (overlap setup latency)
    const int base = blockIdx.x * 512 + tid;
    const bool full = (blockIdx.x * 512 + 512) <= n4;
    float4 xa, xb, ma, mb;
    if (full) {
        xa = x4[base];       ma = m4[base];
        xb = x4[base + 256]; mb = m4[base + 256];
    } else {
        if (base < n4)       { xa = x4[base];       ma = m4[base]; }
        if (base + 256 < n4) { xb = x4[base + 256]; mb = m4[base + 256]; }
    }

    ((float4*)s_emid)[tid] = ev;
    ((uint4*)s_epos)[tid]  = pv;
    if (tid < 64) { s_cb[tid] = cbv; s_mid[tid] = midv; }
    __syncthreads();

    const float lo    = s_cb[0];
    const float range = s_cb[63] - lo;
    const float scale = (range > 0.0f) ? ((float)NCELL / range) : 0.0f;

    float xr[8] = { xa.x, xa.y, xa.z, xa.w, xb.x, xb.y, xb.z, xb.w };
    float mr[8] = { ma.x, ma.y, ma.z, ma.w, mb.x, mb.y, mb.z, mb.w };
    float sv[8], yv[8];

#pragma unroll
    for (int k = 0; k < 8; ++k) {
        const float m = mr[k];
        const float r = xr[k] - m;
        const int   c = cellof(r, lo, scale);
        const float        emid = s_emid[c];   // independent b32 reads,
        const unsigned int ep   = s_epos[c];   // full 32-bank spread
        const int pos0 = (int)(ep & 0xFFFFu);
        const int n    = (int)(ep >> 16);
        int pos = pos0 + ((emid < r) ? 1 : 0);
        if (n > 1) {                            // rare per-lane fixup
            for (int j = 1; j < n; ++j)
                pos += (s_mid[pos0 + j] < r) ? 1 : 0;
        }
        sv[k] = (float)pos;
        yv[k] = s_cb[pos] + m;
    }

    if (full) {
        sym_out[base]         = make_float4(sv[0], sv[1], sv[2], sv[3]);
        yhat_out[base]        = make_float4(yv[0], yv[1], yv[2], yv[3]);
        sym_out[base + 256]   = make_float4(sv[4], sv[5], sv[6], sv[7]);
        yhat_out[base + 256]  = make_float4(yv[4], yv[5], yv[6], yv[7]);
    } else {
        if (base < n4) {
            sym_out[base]  = make_float4(sv[0], sv[1], sv[2], sv[3]);
            yhat_out[base] = make_float4(yv[0], yv[1], yv[2], yv[3]);
        }
        if (base + 256 < n4) {
            sym_out[base + 256]  = make_float4(sv[4], sv[5], sv[6], sv[7]);
            yhat_out[base + 256] = make_float4(yv[4], yv[5], yv[6], yv[7]);
        }
    }
}

extern "C" void kernel_launch(void* const* d_in, const int* in_sizes, int n_in,
                              void* d_out, int out_size, void* d_ws, size_t ws_size,
                              hipStream_t stream)
{
    const float* x     = (const float*)d_in[0];
    const float* means = (const float*)d_in[1];
    const float* cb    = (const float*)d_in[2];

    const int n  = in_sizes[0];      // 25,165,824
    const int n4 = n / 4;            // 6,291,456 (divisible)

    float* out = (float*)d_out;      // [0..n): symbols (as float), [n..2n): y_hat

    // workspace layout: mid f32[64] | emid f32[1024] | epos u32[1024]
    float*        ws_mid  = (float*)d_ws;
    float*        ws_emid = (float*)((char*)d_ws + 256);
    unsigned int* ws_epos = (unsigned int*)((char*)d_ws + 256 + 4096);

    build_lut_kernel<<<1, 256, 0, stream>>>(cb, ws_mid, ws_emid, ws_epos);

    const int block = 256;
    const int grid  = (n4 + 511) / 512;   // 12288: flat grid, quick retire
    quant_dequant_kernel<<<grid, block, 0, stream>>>(
        (const float4*)x, (const float4*)means, cb,
        ws_mid, (const float4*)ws_emid, (const uint4*)ws_epos,
        (float4*)out, (float4*)(out + n), n4);
}